// Round 2
// baseline (7922.005 us; speedup 1.0000x reference)
//
#include <hip/hip_runtime.h>
#include <hip/hip_bf16.h>
#include <cstdint>
#include <cstddef>

#define DIM 4096
#define HIDDEN 11008
#define MTOK 8192   // B*S = 4*2048

typedef __bf16 bf16x8 __attribute__((ext_vector_type(8)));
typedef float floatx4 __attribute__((ext_vector_type(4)));

__device__ __forceinline__ unsigned short f2bf(float f) {
    union { float f; unsigned int u; } v; v.f = f;
    unsigned int r = v.u + 0x7FFFu + ((v.u >> 16) & 1u);
    return (unsigned short)(r >> 16);
}

__device__ __forceinline__ floatx4 mfma16(bf16x8 a, bf16x8 b, floatx4 c) {
    return __builtin_amdgcn_mfma_f32_16x16x32_bf16(a, b, c, 0, 0, 0);
}

// ---------------- conversion kernels ----------------

__global__ void cvt_f32_bf16(const float4* __restrict__ in, ushort4* __restrict__ out, int n4) {
    int i = blockIdx.x * 256 + threadIdx.x;
    if (i < n4) {
        float4 v = in[i];
        ushort4 o;
        o.x = f2bf(v.x); o.y = f2bf(v.y); o.z = f2bf(v.z); o.w = f2bf(v.w);
        out[i] = o;
    }
}

__global__ void cvt_i32_bf16(const int4* __restrict__ in, ushort4* __restrict__ out, int n4) {
    int i = blockIdx.x * 256 + threadIdx.x;
    if (i < n4) {
        int4 v = in[i];
        ushort4 o;
        o.x = f2bf((float)v.x); o.y = f2bf((float)v.y);
        o.z = f2bf((float)v.z); o.w = f2bf((float)v.w);
        out[i] = o;
    }
}

// ---------------- GEMM1: fused gate+up+SwiGLU, LDS-free ----------------
// A [MTOK,DIM] bf16; Bg,Bu [HIDDEN,DIM] bf16 (NT, K contiguous).
// Block 128m x 64n, 4 waves (2x2), each wave 64m x 32n for BOTH gate & up.
// Fragments loaded straight from global: one dwordx4 per lane covers
// 16 rows x 64B fully-used cachelines. No LDS, no barriers.
__global__ __launch_bounds__(256) void gemm_gateup(
    const unsigned short* __restrict__ A,
    const unsigned short* __restrict__ Bg,
    const unsigned short* __restrict__ Bu,
    unsigned short* __restrict__ mid,
    const float* __restrict__ sgp, const float* __restrict__ sup)
{
    const int tid  = threadIdx.x;
    const int lane = tid & 63;
    const int wave = tid >> 6;
    const int wr   = wave >> 1;     // 0..1 : 64-row half
    const int wc   = wave & 1;      // 0..1 : 32-col half
    const int quad = lane >> 4;     // 0..3 : k-octet
    const int l16  = lane & 15;

    const size_t m0 = (size_t)blockIdx.x * 128;
    const size_t n0 = (size_t)blockIdx.y * 64;

    // per-lane fragment base pointers (k = quad*8 within each K32 tile)
    const unsigned short* pA[4];
    const unsigned short* pG[2];
    const unsigned short* pU[2];
    for (int i = 0; i < 4; ++i)
        pA[i] = A + (m0 + wr * 64 + i * 16 + l16) * DIM + quad * 8;
    for (int j = 0; j < 2; ++j) {
        const size_t row = n0 + wc * 32 + j * 16 + l16;
        pG[j] = Bg + row * DIM + quad * 8;
        pU[j] = Bu + row * DIM + quad * 8;
    }

    floatx4 accg[4][2], accu[4][2];
    const floatx4 zero = {0.f, 0.f, 0.f, 0.f};
    for (int i = 0; i < 4; ++i)
        for (int j = 0; j < 2; ++j) { accg[i][j] = zero; accu[i][j] = zero; }

    constexpr int NK = DIM / 32;   // 128

    bf16x8 fA[2][4], fG[2][2], fU[2][2];
    for (int i = 0; i < 4; ++i) fA[0][i] = *(const bf16x8*)pA[i];
    for (int j = 0; j < 2; ++j) {
        fG[0][j] = *(const bf16x8*)pG[j];
        fU[0][j] = *(const bf16x8*)pU[j];
    }

    #pragma unroll 2
    for (int kt = 0; kt < NK; ++kt) {
        const int cur = kt & 1, nxt = cur ^ 1;
        const size_t off = (size_t)((kt + 1 < NK) ? (kt + 1) : kt) * 32;
        // prefetch next K32 tile (stays in flight across the MFMAs below)
        for (int i = 0; i < 4; ++i) fA[nxt][i] = *(const bf16x8*)(pA[i] + off);
        for (int j = 0; j < 2; ++j) {
            fG[nxt][j] = *(const bf16x8*)(pG[j] + off);
            fU[nxt][j] = *(const bf16x8*)(pU[j] + off);
        }
        for (int i = 0; i < 4; ++i)
            for (int j = 0; j < 2; ++j) {
                accg[i][j] = mfma16(fA[cur][i], fG[cur][j], accg[i][j]);
                accu[i][j] = mfma16(fA[cur][i], fU[cur][j], accu[i][j]);
            }
    }

    const float s_g = *sgp;
    const float s_u = *sup;
    // C/D layout: col = lane&15 (N), row = quad*4 + reg (M)
    for (int i = 0; i < 4; ++i) {
        const size_t row = m0 + wr * 64 + i * 16 + quad * 4;
        for (int j = 0; j < 2; ++j) {
            const size_t col = n0 + wc * 32 + j * 16 + l16;
            for (int r = 0; r < 4; ++r) {
                float g = accg[i][j][r] * s_g;
                float u = accu[i][j][r] * s_u;
                float sig = 1.0f / (1.0f + __expf(-g));
                float v = g * sig * u;
                mid[(row + r) * HIDDEN + col] = f2bf(v);
            }
        }
    }
}

// ---------------- GEMM2: down projection, LDS-free ----------------
// A = mid [MTOK,HIDDEN] bf16; B = w_down [DIM,HIDDEN] bf16 (NT).
// Block 128x128, 4 waves (2x2), each wave 64x64. fp32 output with scale.
__global__ __launch_bounds__(256) void gemm_down(
    const unsigned short* __restrict__ A,
    const unsigned short* __restrict__ B,
    float* __restrict__ out,
    const float* __restrict__ sdp)
{
    const int tid  = threadIdx.x;
    const int lane = tid & 63;
    const int wave = tid >> 6;
    const int wr   = wave >> 1;
    const int wc   = wave & 1;
    const int quad = lane >> 4;
    const int l16  = lane & 15;

    const size_t m0 = (size_t)blockIdx.x * 128;
    const size_t n0 = (size_t)blockIdx.y * 128;

    const unsigned short* pA[4];
    const unsigned short* pB[4];
    for (int i = 0; i < 4; ++i) {
        pA[i] = A + (m0 + wr * 64 + i * 16 + l16) * HIDDEN + quad * 8;
        pB[i] = B + (n0 + wc * 64 + i * 16 + l16) * HIDDEN + quad * 8;
    }

    floatx4 acc[4][4];
    const floatx4 zero = {0.f, 0.f, 0.f, 0.f};
    for (int i = 0; i < 4; ++i)
        for (int j = 0; j < 4; ++j) acc[i][j] = zero;

    constexpr int NK = HIDDEN / 32;   // 344

    bf16x8 fA[2][4], fB[2][4];
    for (int i = 0; i < 4; ++i) {
        fA[0][i] = *(const bf16x8*)pA[i];
        fB[0][i] = *(const bf16x8*)pB[i];
    }

    #pragma unroll 2
    for (int kt = 0; kt < NK; ++kt) {
        const int cur = kt & 1, nxt = cur ^ 1;
        const size_t off = (size_t)((kt + 1 < NK) ? (kt + 1) : kt) * 32;
        for (int i = 0; i < 4; ++i) {
            fA[nxt][i] = *(const bf16x8*)(pA[i] + off);
            fB[nxt][i] = *(const bf16x8*)(pB[i] + off);
        }
        for (int i = 0; i < 4; ++i)
            for (int j = 0; j < 4; ++j)
                acc[i][j] = mfma16(fA[cur][i], fB[cur][j], acc[i][j]);
    }

    const float s_d = *sdp;
    for (int i = 0; i < 4; ++i) {
        const size_t row = m0 + wr * 64 + i * 16 + quad * 4;
        for (int j = 0; j < 4; ++j) {
            const size_t col = n0 + wc * 64 + j * 16 + l16;
            for (int r = 0; r < 4; ++r)
                out[(row + r) * DIM + col] = acc[i][j][r] * s_d;
        }
    }
}

// ---------------- launch ----------------

extern "C" void kernel_launch(void* const* d_in, const int* in_sizes, int n_in,
                              void* d_out, int out_size, void* d_ws, size_t ws_size,
                              hipStream_t stream) {
    const float* x  = (const float*)d_in[0];
    const int*   wg = (const int*)d_in[1];
    const int*   wu = (const int*)d_in[2];
    const int*   wd = (const int*)d_in[3];
    const float* sg = (const float*)d_in[4];
    const float* su = (const float*)d_in[5];
    const float* sd = (const float*)d_in[6];
    float* out = (float*)d_out;

    // workspace carve-up (all bf16 as ushort). Total = 517,996,544 bytes.
    unsigned short* xb   = (unsigned short*)d_ws;
    unsigned short* wgb  = xb  + (size_t)MTOK * DIM;
    unsigned short* wub  = wgb + (size_t)HIDDEN * DIM;
    unsigned short* wdb  = wub + (size_t)HIDDEN * DIM;
    unsigned short* midb = wdb + (size_t)DIM * HIDDEN;

    // 1) dtype conversions (weights are ints in [-127,127] -> exact in bf16)
    {
        int n4 = MTOK * DIM / 4;
        cvt_f32_bf16<<<dim3((n4 + 255) / 256), 256, 0, stream>>>((const float4*)x, (ushort4*)xb, n4);
    }
    {
        int n4 = HIDDEN * DIM / 4;
        cvt_i32_bf16<<<dim3((n4 + 255) / 256), 256, 0, stream>>>((const int4*)wg, (ushort4*)wgb, n4);
        cvt_i32_bf16<<<dim3((n4 + 255) / 256), 256, 0, stream>>>((const int4*)wu, (ushort4*)wub, n4);
        cvt_i32_bf16<<<dim3((n4 + 255) / 256), 256, 0, stream>>>((const int4*)wd, (ushort4*)wdb, n4);
    }

    // 2) fused gate+up GEMM + SwiGLU -> mid (bf16)
    gemm_gateup<<<dim3(MTOK / 128, HIDDEN / 64), 256, 0, stream>>>(xb, wgb, wub, midb, sg, su);

    // 3) down GEMM -> out (fp32)
    gemm_down<<<dim3(MTOK / 128, DIM / 128), 256, 0, stream>>>(midb, wdb, out, sd);
}